// Round 11
// baseline (50.637 us; speedup 1.0000x reference)
//
#include <hip/hip_runtime.h>

#define NODES 255
#define IN_DIM 512
#define ODIM 64
#define BM 64

typedef __attribute__((ext_vector_type(8))) short short8v;
typedef __attribute__((ext_vector_type(4))) float f32x4;
typedef __attribute__((ext_vector_type(4))) unsigned int u32x4;
typedef unsigned short u16;
typedef unsigned int u32;

__device__ __forceinline__ u16 f32_bf16(float f) {
  u32 u = __builtin_bit_cast(u32, f);
  u += 0x7FFFu + ((u >> 16) & 1u);
  return (u16)(u >> 16);
}
__device__ __forceinline__ float bf16_f32(u16 h) {
  u32 u = ((u32)h) << 16;
  return __builtin_bit_cast(float, u);
}

// Fragment-linear pre-split (same as R5/R9):
//  W: frag(kc 0..15, nb 0..15): elem(lane,j) = W[node=nb*16+(lane&15)][k=kc*32+(lane>>4)*8+j]
//     at linear ((kc*16+nb)*64+lane)*8+j
//  AT: frag(kc4 0..7, nb 0..3): elem(lane,j) = A[leaf=kc4*32+(lane>>4)*8+j][col=nb*16+(lane&15)]
//     at linear ((kc4*4+nb)*64+lane)*8+j
__global__ __launch_bounds__(256) void prep_kernel(
    const float* __restrict__ layers, const float* __restrict__ aprobs,
    u16* __restrict__ Wfh, u16* __restrict__ Wfl,
    u16* __restrict__ ATfh, u16* __restrict__ ATfl) {
  int id = blockIdx.x * 256 + threadIdx.x;
  if (id < 131072) {
    const int j = id & 7;
    const int lane = (id >> 3) & 63;
    const int nb = (id >> 9) & 15;
    const int kc = id >> 13;
    const int node = nb * 16 + (lane & 15);
    const int k = kc * 32 + ((lane >> 4) << 3) + j;
    const float v = (node < NODES) ? layers[node * IN_DIM + k] : 0.f;
    const u16 h = f32_bf16(v);
    Wfh[id] = h;
    Wfl[id] = f32_bf16(v - bf16_f32(h));
  } else if (id < 131072 + 16384) {
    const int t = id - 131072;
    const int j = t & 7;
    const int lane = (t >> 3) & 63;
    const int nb = (t >> 9) & 3;
    const int kc4 = t >> 11;
    const int c = nb * 16 + (lane & 15);
    const int leaf = kc4 * 32 + ((lane >> 4) << 3) + j;
    const float v = aprobs[leaf * ODIM + c];
    const u16 h = f32_bf16(v);
    ATfh[t] = h;
    ATfl[t] = f32_bf16(v - bf16_f32(h));
  }
}

// 512 threads (8 waves), BM=64 rows/block, grid 512, 2 blocks/CU.
// Phase 1: BK=128, 4 iters, 1 barrier each; T14 order (prefetch->compute->stage-late).
// LDS 64KB union: phase 1 x dbuf bf16 hi/lo (2 x 32KB: buf b hi at b*16384 u16, lo +8192);
// phase 2+ s_sig f32[64][256]; phase 4 partials f32[64][64].
__global__ __launch_bounds__(512, 4) void prolo_main(
    const float* __restrict__ x, const float* __restrict__ comp,
    const float* __restrict__ alpha,
    const u16* __restrict__ Wfh, const u16* __restrict__ Wfl,
    const u16* __restrict__ ATfh, const u16* __restrict__ ATfl,
    float* __restrict__ out) {
  __shared__ __align__(16) unsigned char smem[65536];
  float* s_sig = (float*)smem;
  u16* sA = (u16*)smem;

  const int tid = threadIdx.x;
  const int lane = tid & 63;
  const int w = tid >> 6;
  const int l15 = lane & 15;
  const int lq = lane >> 4;
  const int row0 = blockIdx.x * BM;
  const float alphav = alpha[0];

  // prefetch comparators for phase 2
  const int col0 = (w << 5) + l15;
  const int col1 = col0 + 16;
  const float cv0 = (col0 < NODES) ? comp[col0] : 0.f;
  const float cv1 = (col1 < NODES) ? comp[col1] : 0.f;

  // ---------- Phase 1: z GEMM. Wave w owns nodes [32w, 32w+32), all 64 rows.
  f32x4 acc[4][2];
#pragma unroll
  for (int i = 0; i < 4; ++i)
#pragma unroll
    for (int j = 0; j < 2; ++j) acc[i][j] = {0.f, 0.f, 0.f, 0.f};

  const int srow = tid >> 3;            // staging row 0..63
  const int k0 = (tid & 7) << 4;        // staging k 0..112 (16 floats per thread per chunk)
  const int sw8 = (srow & 7) << 3;
  const int g0 = k0 ^ sw8;              // 16-elem-aligned ^ 8-aligned -> 8-aligned
  const int sbase = srow * 128;
  const float* xbase = x + (size_t)(row0 + srow) * IN_DIM + k0;

  f32x4 va[4], vb[4];

#define LOAD16(DST, P)                                     \
  {                                                        \
    DST[0] = *reinterpret_cast<const f32x4*>(P);           \
    DST[1] = *reinterpret_cast<const f32x4*>((P) + 4);     \
    DST[2] = *reinterpret_cast<const f32x4*>((P) + 8);     \
    DST[3] = *reinterpret_cast<const f32x4*>((P) + 12);    \
  }

#define STAGE(V, BUF)                                                         \
  {                                                                           \
    u32 H[8], L[8];                                                           \
    _Pragma("unroll") for (int q = 0; q < 8; ++q) {                           \
      const float fa = V[q >> 1][(q & 1) * 2 + 0];                            \
      const float fb = V[q >> 1][(q & 1) * 2 + 1];                            \
      const u16 ha = f32_bf16(fa), hb = f32_bf16(fb);                         \
      const u16 la = f32_bf16(fa - bf16_f32(ha));                             \
      const u16 lb = f32_bf16(fb - bf16_f32(hb));                             \
      H[q] = (u32)ha | ((u32)hb << 16);                                       \
      L[q] = (u32)la | ((u32)lb << 16);                                       \
    }                                                                         \
    u16* bh = sA + (BUF)*16384 + sbase;                                       \
    u16* bl = bh + 8192;                                                      \
    *reinterpret_cast<u32x4*>(bh + g0) = u32x4{H[0], H[1], H[2], H[3]};       \
    *reinterpret_cast<u32x4*>(bh + (g0 ^ 8)) = u32x4{H[4], H[5], H[6], H[7]}; \
    *reinterpret_cast<u32x4*>(bl + g0) = u32x4{L[0], L[1], L[2], L[3]};       \
    *reinterpret_cast<u32x4*>(bl + (g0 ^ 8)) = u32x4{L[4], L[5], L[6], L[7]}; \
  }

  const int wfbase = (w << 10) + (lane << 3);

  short8v whA[2], wlA[2], whB[2], wlB[2];

#define LOADW(WH, WL, KC)                                                     \
  {                                                                           \
    _Pragma("unroll") for (int ntl = 0; ntl < 2; ++ntl) {                     \
      const int fb = ((KC) << 13) + wfbase + (ntl << 9);                      \
      WH[ntl] = *reinterpret_cast<const short8v*>(Wfh + fb);                  \
      WL[ntl] = *reinterpret_cast<const short8v*>(Wfl + fb);                  \
    }                                                                         \
  }

// One k-step (K=32): compute with (WH,WL); optionally preload (WHN,WLN) for KCN.
#define KQC(WH, WL, KQ, BUF, DOLOAD, WHN, WLN, KCN)                           \
  {                                                                           \
    if (DOLOAD) { LOADW(WHN, WLN, KCN) }                                      \
    __builtin_amdgcn_s_setprio(1);                                            \
    _Pragma("unroll") for (int mt = 0; mt < 4; ++mt) {                        \
      const int r = (mt << 4) + l15;                                          \
      const int aoff = r * 128 + ((((KQ) << 5) + (lq << 3)) ^ ((r & 7) << 3));\
      const short8v ah = *reinterpret_cast<const short8v*>(sA + (BUF)*16384 + aoff);         \
      const short8v al = *reinterpret_cast<const short8v*>(sA + (BUF)*16384 + 8192 + aoff);  \
      _Pragma("unroll") for (int ntl = 0; ntl < 2; ++ntl) {                   \
        acc[mt][ntl] = __builtin_amdgcn_mfma_f32_16x16x32_bf16(ah, WH[ntl], acc[mt][ntl], 0, 0, 0); \
        acc[mt][ntl] = __builtin_amdgcn_mfma_f32_16x16x32_bf16(ah, WL[ntl], acc[mt][ntl], 0, 0, 0); \
        acc[mt][ntl] = __builtin_amdgcn_mfma_f32_16x16x32_bf16(al, WH[ntl], acc[mt][ntl], 0, 0, 0); \
      }                                                                       \
    }                                                                         \
    __builtin_amdgcn_s_setprio(0);                                            \
  }

  // prologue: chunks 0,1 to regs; stage chunk 0; preload W kc=0
  LOAD16(va, xbase);
  LOAD16(vb, xbase + 128);
  STAGE(va, 0);
  LOADW(whA, wlA, 0);
  __syncthreads();

  // chunk 0 (buf 0), kc 0..3
  LOAD16(va, xbase + 256);  // chunk 2
  KQC(whA, wlA, 0, 0, 1, whB, wlB, 1)
  KQC(whB, wlB, 1, 0, 1, whA, wlA, 2)
  KQC(whA, wlA, 2, 0, 1, whB, wlB, 3)
  KQC(whB, wlB, 3, 0, 1, whA, wlA, 4)
  STAGE(vb, 1);             // chunk 1 -> buf 1 (late write, T14)
  __syncthreads();

  // chunk 1 (buf 1), kc 4..7
  LOAD16(vb, xbase + 384);  // chunk 3
  KQC(whA, wlA, 0, 1, 1, whB, wlB, 5)
  KQC(whB, wlB, 1, 1, 1, whA, wlA, 6)
  KQC(whA, wlA, 2, 1, 1, whB, wlB, 7)
  KQC(whB, wlB, 3, 1, 1, whA, wlA, 8)
  STAGE(va, 0);             // chunk 2 -> buf 0
  __syncthreads();

  // chunk 2 (buf 0), kc 8..11
  KQC(whA, wlA, 0, 0, 1, whB, wlB, 9)
  KQC(whB, wlB, 1, 0, 1, whA, wlA, 10)
  KQC(whA, wlA, 2, 0, 1, whB, wlB, 11)
  KQC(whB, wlB, 3, 0, 1, whA, wlA, 12)
  STAGE(vb, 1);             // chunk 3 -> buf 1
  __syncthreads();

  // chunk 3 (buf 1), kc 12..15
  KQC(whA, wlA, 0, 1, 1, whB, wlB, 13)
  KQC(whB, wlB, 1, 1, 1, whA, wlA, 14)
  KQC(whA, wlA, 2, 1, 1, whB, wlB, 15)
  KQC(whB, wlB, 3, 1, 0, whA, wlA, 0)
  __syncthreads();

  // ---------- Phase 2: sigmoid((z-c)*alpha) -> s_sig (col ^ (row&15) swizzle)
#pragma unroll
  for (int ntl = 0; ntl < 2; ++ntl) {
    const int col = (w << 5) + (ntl << 4) + l15;
    const float cv = ntl ? cv1 : cv0;
#pragma unroll
    for (int mt = 0; mt < 4; ++mt) {
#pragma unroll
      for (int r4 = 0; r4 < 4; ++r4) {
        const int r = (mt << 4) + (lq << 2) + r4;
        const float z = (acc[mt][ntl][r4] - cv) * alphav;
        const float s = 1.f / (1.f + __expf(-z));
        s_sig[(r << 8) + (col ^ (r & 15))] = s;
      }
    }
  }
  __syncthreads();

  // ---------- Phase 3+4: in-register leaf probs feeding p@A MFMA.
  const int mt3 = w & 3;
  const int kh = w >> 2;
  const int arow = (mt3 << 4) + l15;
  const float* srow_p = s_sig + (arow << 8);
  const int sw = arow & 15;

  f32x4 acc2[4];
#pragma unroll
  for (int i = 0; i < 4; ++i) acc2[i] = {0.f, 0.f, 0.f, 0.f};

#pragma unroll
  for (int ks = 0; ks < 4; ++ks) {
    // hoist all 8 AT fragment loads — tree walk covers L2 latency
    short8v bhv[4], blv[4];
#pragma unroll
    for (int nt = 0; nt < 4; ++nt) {
      const int fb = ((((kh << 2) + ks) << 2) + nt) * 512 + (lane << 3);
      bhv[nt] = *reinterpret_cast<const short8v*>(ATfh + fb);
      blv[nt] = *reinterpret_cast<const short8v*>(ATfl + fb);
    }

    const int lb = (kh << 7) + (ks << 5) + (lq << 3);
    float P = 1.f;
#pragma unroll
    for (int n = 0; n < 5; ++n) {
      const int node = (1 << n) - 1 + (lb >> (8 - n));
      const float s = srow_p[node ^ sw];
      P *= ((lb >> (7 - n)) & 1) ? (1.f - s) : s;
    }
    const float s5 = srow_p[(31 + (lb >> 3)) ^ sw];
    const int n6 = 63 + (lb >> 2);
    const float s6a = srow_p[n6 ^ sw];
    const float s6b = srow_p[(n6 + 1) ^ sw];
    const int n7 = 127 + (lb >> 1);
    const float s7_0 = srow_p[n7 ^ sw];
    const float s7_1 = srow_p[(n7 + 1) ^ sw];
    const float s7_2 = srow_p[(n7 + 2) ^ sw];
    const float s7_3 = srow_p[(n7 + 3) ^ sw];
    const float q0 = P * s5, q1 = P - P * s5;
    const float r00 = q0 * s6a, r01 = q0 - q0 * s6a;
    const float r10 = q1 * s6b, r11 = q1 - q1 * s6b;
    float p[8];
    p[0] = r00 * s7_0; p[1] = r00 - p[0];
    p[2] = r01 * s7_1; p[3] = r01 - p[2];
    p[4] = r10 * s7_2; p[5] = r10 - p[4];
    p[6] = r11 * s7_3; p[7] = r11 - p[6];
    short8v pah, pal;
#pragma unroll
    for (int j = 0; j < 8; ++j) {
      const u16 h = f32_bf16(p[j]);
      pah[j] = (short)h;
      pal[j] = (short)f32_bf16(p[j] - bf16_f32(h));
    }
#pragma unroll
    for (int nt = 0; nt < 4; ++nt) {
      acc2[nt] = __builtin_amdgcn_mfma_f32_16x16x32_bf16(pah, bhv[nt], acc2[nt], 0, 0, 0);
      acc2[nt] = __builtin_amdgcn_mfma_f32_16x16x32_bf16(pah, blv[nt], acc2[nt], 0, 0, 0);
      acc2[nt] = __builtin_amdgcn_mfma_f32_16x16x32_bf16(pal, bhv[nt], acc2[nt], 0, 0, 0);
    }
  }
  __syncthreads();  // all waves done reading s_sig

  // K-half combine via smem partials (aliases s_sig, now dead)
  float* part = (float*)smem;  // [64][64] f32
  if (kh == 1) {
#pragma unroll
    for (int nt = 0; nt < 4; ++nt)
#pragma unroll
      for (int r4 = 0; r4 < 4; ++r4)
        part[(((mt3 << 4) + (lq << 2) + r4) << 6) + (nt << 4) + l15] = acc2[nt][r4];
  }
  __syncthreads();

  if (kh == 0) {
#pragma unroll
    for (int r4 = 0; r4 < 4; ++r4) {
      const int rloc = (mt3 << 4) + (lq << 2) + r4;
      float v0 = acc2[0][r4] + part[(rloc << 6) + l15];
      float v1 = acc2[1][r4] + part[(rloc << 6) + 16 + l15];
      float v2 = acc2[2][r4] + part[(rloc << 6) + 32 + l15];
      float v3 = acc2[3][r4] + part[(rloc << 6) + 48 + l15];
      float m = fmaxf(fmaxf(v0, v1), fmaxf(v2, v3));
#pragma unroll
      for (int d = 1; d < 16; d <<= 1) m = fmaxf(m, __shfl_xor(m, d, 64));
      float e0 = __expf(v0 - m), e1 = __expf(v1 - m), e2 = __expf(v2 - m), e3 = __expf(v3 - m);
      float ssum = e0 + e1 + e2 + e3;
#pragma unroll
      for (int d = 1; d < 16; d <<= 1) ssum += __shfl_xor(ssum, d, 64);
      const float inv = 1.f / ssum;
      float* op = out + (size_t)(row0 + rloc) * ODIM + l15;
      op[0] = e0 * inv;
      op[16] = e1 * inv;
      op[32] = e2 * inv;
      op[48] = e3 * inv;
    }
  }
}

extern "C" void kernel_launch(void* const* d_in, const int* in_sizes, int n_in,
                              void* d_out, int out_size, void* d_ws, size_t ws_size,
                              hipStream_t stream) {
  const float* x      = (const float*)d_in[0];
  const float* layers = (const float*)d_in[1];
  const float* comp   = (const float*)d_in[2];
  const float* alpha  = (const float*)d_in[3];
  const float* aprobs = (const float*)d_in[4];
  float* out = (float*)d_out;

  const size_t wsplit = (size_t)131072;
  const size_t atsz   = (size_t)16384;
  if (ws_size < (2 * wsplit + 2 * atsz) * sizeof(u16)) return;

  u16* Wfh  = (u16*)d_ws;
  u16* Wfl  = Wfh + wsplit;
  u16* ATfh = Wfl + wsplit;
  u16* ATfl = ATfh + atsz;

  const int prep_items = 131072 + 16384;
  prep_kernel<<<dim3((prep_items + 255) / 256), dim3(256), 0, stream>>>(
      layers, aprobs, Wfh, Wfl, ATfh, ATfl);

  prolo_main<<<dim3(32768 / BM), dim3(512), 0, stream>>>(
      x, comp, alpha, Wfh, Wfl, ATfh, ATfl, out);
}

// Round 12
// 42.414 us; speedup vs baseline: 1.1939x; 1.1939x over previous
//
#include <hip/hip_runtime.h>

#define NODES 255
#define IN_DIM 512
#define ODIM 64
#define BM 64

typedef __attribute__((ext_vector_type(8))) short short8v;
typedef __attribute__((ext_vector_type(4))) float f32x4;
typedef __attribute__((ext_vector_type(4))) unsigned int u32x4;
typedef unsigned short u16;
typedef unsigned int u32;

__device__ __forceinline__ u16 f32_bf16(float f) {
  u32 u = __builtin_bit_cast(u32, f);
  u += 0x7FFFu + ((u >> 16) & 1u);
  return (u16)(u >> 16);
}
__device__ __forceinline__ float bf16_f32(u16 h) {
  u32 u = ((u32)h) << 16;
  return __builtin_bit_cast(float, u);
}

// Fragment-linear pre-split (same as R5/R9):
//  W: frag(kc 0..15, nb 0..15): elem(lane,j) = W[node=nb*16+(lane&15)][k=kc*32+(lane>>4)*8+j]
//     at linear ((kc*16+nb)*64+lane)*8+j
//  AT: frag(kc4 0..7, nb 0..3): elem(lane,j) = A[leaf=kc4*32+(lane>>4)*8+j][col=nb*16+(lane&15)]
//     at linear ((kc4*4+nb)*64+lane)*8+j
__global__ __launch_bounds__(256) void prep_kernel(
    const float* __restrict__ layers, const float* __restrict__ aprobs,
    u16* __restrict__ Wfh, u16* __restrict__ Wfl,
    u16* __restrict__ ATfh, u16* __restrict__ ATfl) {
  int id = blockIdx.x * 256 + threadIdx.x;
  if (id < 131072) {
    const int j = id & 7;
    const int lane = (id >> 3) & 63;
    const int nb = (id >> 9) & 15;
    const int kc = id >> 13;
    const int node = nb * 16 + (lane & 15);
    const int k = kc * 32 + ((lane >> 4) << 3) + j;
    const float v = (node < NODES) ? layers[node * IN_DIM + k] : 0.f;
    const u16 h = f32_bf16(v);
    Wfh[id] = h;
    Wfl[id] = f32_bf16(v - bf16_f32(h));
  } else if (id < 131072 + 16384) {
    const int t = id - 131072;
    const int j = t & 7;
    const int lane = (t >> 3) & 63;
    const int nb = (t >> 9) & 3;
    const int kc4 = t >> 11;
    const int c = nb * 16 + (lane & 15);
    const int leaf = kc4 * 32 + ((lane >> 4) << 3) + j;
    const float v = aprobs[leaf * ODIM + c];
    const u16 h = f32_bf16(v);
    ATfh[t] = h;
    ATfl[t] = f32_bf16(v - bf16_f32(h));
  }
}

// 512 threads (8 waves), BM=64 rows/block, grid 512, 2 blocks/CU (R9-proven).
// LDS 64KB union: phase 1 x dbuf bf16 hi/lo (32KB); phase 2+ s_sig f32[64][256];
// phase 4 partials f32[64][64].
// R12 delta vs R9: phase 3/4 use SINGLE-bf16 p (2-term p@A), cutting the
// dominant tree-walk VALU (p hi/lo split+pack) and 1/3 of phase-4 MFMAs.
__global__ __launch_bounds__(512, 4) void prolo_main(
    const float* __restrict__ x, const float* __restrict__ comp,
    const float* __restrict__ alpha,
    const u16* __restrict__ Wfh, const u16* __restrict__ Wfl,
    const u16* __restrict__ ATfh, const u16* __restrict__ ATfl,
    float* __restrict__ out) {
  __shared__ __align__(16) unsigned char smem[65536];
  float* s_sig = (float*)smem;
  u16* sA = (u16*)smem;  // buf b: hi at b*8192, lo at b*8192+4096 (u16 units)

  const int tid = threadIdx.x;
  const int lane = tid & 63;
  const int w = tid >> 6;
  const int l15 = lane & 15;
  const int lq = lane >> 4;
  const int row0 = blockIdx.x * BM;
  const float alphav = alpha[0];

  // prefetch comparators for phase 2
  const int col0 = (w << 5) + l15;
  const int col1 = col0 + 16;
  const float cv0 = (col0 < NODES) ? comp[col0] : 0.f;
  const float cv1 = (col1 < NODES) ? comp[col1] : 0.f;

  // ---------- Phase 1: z GEMM. Wave w owns nodes [32w, 32w+32), all 64 rows.
  f32x4 acc[4][2];
#pragma unroll
  for (int i = 0; i < 4; ++i)
#pragma unroll
    for (int j = 0; j < 2; ++j) acc[i][j] = {0.f, 0.f, 0.f, 0.f};

  const int srow = tid >> 3;            // staging row 0..63
  const int k0 = (tid & 7) << 3;        // staging k 0..56
  const int soff = srow * 64 + (k0 ^ ((srow & 7) << 3));
  const float* xbase = x + (size_t)(row0 + srow) * IN_DIM + k0;

  // 2-deep register prefetch (chunk = 64 k-columns; 8 floats/thread)
  f32x4 vA0 = *reinterpret_cast<const f32x4*>(xbase);
  f32x4 vA1 = *reinterpret_cast<const f32x4*>(xbase + 4);
  f32x4 vB0 = *reinterpret_cast<const f32x4*>(xbase + 64);
  f32x4 vB1 = *reinterpret_cast<const f32x4*>(xbase + 68);

#define STAGE_CHUNK(P0, P1, BUF)                                              \
  {                                                                           \
    u32* dh = reinterpret_cast<u32*>(sA + (BUF)*8192 + soff);                 \
    u32* dl = reinterpret_cast<u32*>(sA + (BUF)*8192 + 4096 + soff);          \
    float ff[8] = {P0[0], P0[1], P0[2], P0[3], P1[0], P1[1], P1[2], P1[3]};   \
    _Pragma("unroll") for (int j = 0; j < 4; ++j) {                           \
      u16 ha = f32_bf16(ff[2 * j]), hb = f32_bf16(ff[2 * j + 1]);             \
      u16 la = f32_bf16(ff[2 * j] - bf16_f32(ha));                            \
      u16 lb = f32_bf16(ff[2 * j + 1] - bf16_f32(hb));                        \
      dh[j] = (u32)ha | ((u32)hb << 16);                                      \
      dl[j] = (u32)la | ((u32)lb << 16);                                      \
    }                                                                         \
  }

  const int wfbase = (w << 10) + (lane << 3);

  // W-fragment register double-buffer: set = 4 frags (one kq half).
  short8v wbhA[2], wblA[2], wbhB[2], wblB[2];

#define LOADW(WH, WL, KS, KQ)                                                 \
  {                                                                           \
    _Pragma("unroll") for (int ntl = 0; ntl < 2; ++ntl) {                     \
      const int fb = ((((KS) << 1) + (KQ)) << 13) + wfbase + (ntl << 9);      \
      WH[ntl] = *reinterpret_cast<const short8v*>(Wfh + fb);                  \
      WL[ntl] = *reinterpret_cast<const short8v*>(Wfl + fb);                  \
    }                                                                         \
  }

#define CHALF(WH, WL, KQ, BUF)                                                \
  {                                                                           \
    _Pragma("unroll") for (int mt = 0; mt < 4; ++mt) {                        \
      const int r = (mt << 4) + l15;                                          \
      const int kk = ((KQ) << 5) + (lq << 3);                                 \
      const int aoff = r * 64 + (kk ^ ((r & 7) << 3));                        \
      const short8v ah = *reinterpret_cast<const short8v*>(sA + (BUF)*8192 + aoff);        \
      const short8v al = *reinterpret_cast<const short8v*>(sA + (BUF)*8192 + 4096 + aoff); \
      _Pragma("unroll") for (int ntl = 0; ntl < 2; ++ntl) {                   \
        acc[mt][ntl] = __builtin_amdgcn_mfma_f32_16x16x32_bf16(ah, WH[ntl], acc[mt][ntl], 0, 0, 0); \
        acc[mt][ntl] = __builtin_amdgcn_mfma_f32_16x16x32_bf16(ah, WL[ntl], acc[mt][ntl], 0, 0, 0); \
        acc[mt][ntl] = __builtin_amdgcn_mfma_f32_16x16x32_bf16(al, WH[ntl], acc[mt][ntl], 0, 0, 0); \
      }                                                                       \
    }                                                                         \
  }

  // prologue
  LOADW(wbhA, wblA, 0, 0);
  STAGE_CHUNK(vA0, vA1, 0);
  __syncthreads();

#pragma unroll
  for (int ks = 0; ks < 8; ++ks) {
    // x prefetch, 2 chunks ahead
    if (ks + 2 < 8) {
      const float* xp = xbase + (ks + 2) * 64;
      vA0 = *reinterpret_cast<const f32x4*>(xp);
      vA1 = *reinterpret_cast<const f32x4*>(xp + 4);
    }
    // issue W loads for this iter's second half before any compute
    LOADW(wbhB, wblB, ks, 1);
    // stage next x chunk (VALU + ds_write) — covers the W-load latency
    if (ks + 1 < 8) STAGE_CHUNK(vB0, vB1, ((ks + 1) & 1));

    // first half-compute (W prefetched last iter / prologue)
    CHALF(wbhA, wblA, 0, (ks & 1));
    // issue next iter's first-half W loads under the second half's MFMAs
    if (ks < 7) LOADW(wbhA, wblA, (ks + 1), 0);
    // second half-compute
    CHALF(wbhB, wblB, 1, (ks & 1));

    {
      f32x4 t0 = vA0, t1 = vA1;
      vA0 = vB0; vA1 = vB1;
      vB0 = t0;  vB1 = t1;
    }
    __syncthreads();
  }

  // ---------- Phase 2: sigmoid((z-c)*alpha) -> s_sig (col ^ (row&15) swizzle)
#pragma unroll
  for (int ntl = 0; ntl < 2; ++ntl) {
    const int col = (w << 5) + (ntl << 4) + l15;
    const float cv = ntl ? cv1 : cv0;
#pragma unroll
    for (int mt = 0; mt < 4; ++mt) {
#pragma unroll
      for (int r4 = 0; r4 < 4; ++r4) {
        const int r = (mt << 4) + (lq << 2) + r4;
        const float z = (acc[mt][ntl][r4] - cv) * alphav;
        const float s = 1.f / (1.f + __expf(-z));
        s_sig[(r << 8) + (col ^ (r & 15))] = s;
      }
    }
  }
  __syncthreads();

  // ---------- Phase 3+4: in-register leaf probs (SINGLE bf16) -> p@A MFMA.
  const int mt3 = w & 3;
  const int kh = w >> 2;
  const int arow = (mt3 << 4) + l15;
  const float* srow_p = s_sig + (arow << 8);
  const int sw = arow & 15;

  f32x4 acc2[4];
#pragma unroll
  for (int i = 0; i < 4; ++i) acc2[i] = {0.f, 0.f, 0.f, 0.f};

#pragma unroll
  for (int ks = 0; ks < 4; ++ks) {
    // hoist all 8 AT fragment loads — tree walk covers L2 latency
    short8v bhv[4], blv[4];
#pragma unroll
    for (int nt = 0; nt < 4; ++nt) {
      const int fb = ((((kh << 2) + ks) << 2) + nt) * 512 + (lane << 3);
      bhv[nt] = *reinterpret_cast<const short8v*>(ATfh + fb);
      blv[nt] = *reinterpret_cast<const short8v*>(ATfl + fb);
    }

    const int lb = (kh << 7) + (ks << 5) + (lq << 3);
    float P = 1.f;
#pragma unroll
    for (int n = 0; n < 5; ++n) {
      const int node = (1 << n) - 1 + (lb >> (8 - n));
      const float s = srow_p[node ^ sw];
      P *= ((lb >> (7 - n)) & 1) ? (1.f - s) : s;
    }
    const float s5 = srow_p[(31 + (lb >> 3)) ^ sw];
    const int n6 = 63 + (lb >> 2);
    const float s6a = srow_p[n6 ^ sw];
    const float s6b = srow_p[(n6 + 1) ^ sw];
    const int n7 = 127 + (lb >> 1);
    const float s7_0 = srow_p[n7 ^ sw];
    const float s7_1 = srow_p[(n7 + 1) ^ sw];
    const float s7_2 = srow_p[(n7 + 2) ^ sw];
    const float s7_3 = srow_p[(n7 + 3) ^ sw];
    const float q0 = P * s5, q1 = P - P * s5;
    const float r00 = q0 * s6a, r01 = q0 - q0 * s6a;
    const float r10 = q1 * s6b, r11 = q1 - q1 * s6b;
    float p[8];
    p[0] = r00 * s7_0; p[1] = r00 - p[0];
    p[2] = r01 * s7_1; p[3] = r01 - p[2];
    p[4] = r10 * s7_2; p[5] = r10 - p[4];
    p[6] = r11 * s7_3; p[7] = r11 - p[6];
    // single-bf16 p fragment (no lo term)
    short8v pah;
#pragma unroll
    for (int j = 0; j < 8; ++j) pah[j] = (short)f32_bf16(p[j]);
#pragma unroll
    for (int nt = 0; nt < 4; ++nt) {
      acc2[nt] = __builtin_amdgcn_mfma_f32_16x16x32_bf16(pah, bhv[nt], acc2[nt], 0, 0, 0);
      acc2[nt] = __builtin_amdgcn_mfma_f32_16x16x32_bf16(pah, blv[nt], acc2[nt], 0, 0, 0);
    }
  }
  __syncthreads();  // all waves done reading s_sig

  // K-half combine via smem partials (aliases s_sig, now dead)
  float* part = (float*)smem;  // [64][64] f32
  if (kh == 1) {
#pragma unroll
    for (int nt = 0; nt < 4; ++nt)
#pragma unroll
      for (int r4 = 0; r4 < 4; ++r4)
        part[(((mt3 << 4) + (lq << 2) + r4) << 6) + (nt << 4) + l15] = acc2[nt][r4];
  }
  __syncthreads();

  if (kh == 0) {
#pragma unroll
    for (int r4 = 0; r4 < 4; ++r4) {
      const int rloc = (mt3 << 4) + (lq << 2) + r4;
      float v0 = acc2[0][r4] + part[(rloc << 6) + l15];
      float v1 = acc2[1][r4] + part[(rloc << 6) + 16 + l15];
      float v2 = acc2[2][r4] + part[(rloc << 6) + 32 + l15];
      float v3 = acc2[3][r4] + part[(rloc << 6) + 48 + l15];
      float m = fmaxf(fmaxf(v0, v1), fmaxf(v2, v3));
#pragma unroll
      for (int d = 1; d < 16; d <<= 1) m = fmaxf(m, __shfl_xor(m, d, 64));
      float e0 = __expf(v0 - m), e1 = __expf(v1 - m), e2 = __expf(v2 - m), e3 = __expf(v3 - m);
      float ssum = e0 + e1 + e2 + e3;
#pragma unroll
      for (int d = 1; d < 16; d <<= 1) ssum += __shfl_xor(ssum, d, 64);
      const float inv = 1.f / ssum;
      float* op = out + (size_t)(row0 + rloc) * ODIM + l15;
      op[0] = e0 * inv;
      op[16] = e1 * inv;
      op[32] = e2 * inv;
      op[48] = e3 * inv;
    }
  }
}

extern "C" void kernel_launch(void* const* d_in, const int* in_sizes, int n_in,
                              void* d_out, int out_size, void* d_ws, size_t ws_size,
                              hipStream_t stream) {
  const float* x      = (const float*)d_in[0];
  const float* layers = (const float*)d_in[1];
  const float* comp   = (const float*)d_in[2];
  const float* alpha  = (const float*)d_in[3];
  const float* aprobs = (const float*)d_in[4];
  float* out = (float*)d_out;

  const size_t wsplit = (size_t)131072;
  const size_t atsz   = (size_t)16384;
  if (ws_size < (2 * wsplit + 2 * atsz) * sizeof(u16)) return;

  u16* Wfh  = (u16*)d_ws;
  u16* Wfl  = Wfh + wsplit;
  u16* ATfh = Wfl + wsplit;
  u16* ATfl = ATfh + atsz;

  const int prep_items = 131072 + 16384;
  prep_kernel<<<dim3((prep_items + 255) / 256), dim3(256), 0, stream>>>(
      layers, aprobs, Wfh, Wfl, ATfh, ATfl);

  prolo_main<<<dim3(32768 / BM), dim3(512), 0, stream>>>(
      x, comp, alpha, Wfh, Wfl, ATfh, ATfl, out);
}

// Round 13
// 38.259 us; speedup vs baseline: 1.3235x; 1.1086x over previous
//
#include <hip/hip_runtime.h>

#define NODES 255
#define IN_DIM 512
#define ODIM 64
#define BM 64

typedef __attribute__((ext_vector_type(8))) short short8v;
typedef __attribute__((ext_vector_type(4))) float f32x4;
typedef unsigned short u16;
typedef unsigned int u32;

__device__ __forceinline__ u16 f32_bf16(float f) {
  u32 u = __builtin_bit_cast(u32, f);
  u += 0x7FFFu + ((u >> 16) & 1u);
  return (u16)(u >> 16);
}
__device__ __forceinline__ float bf16_f32(u16 h) {
  u32 u = ((u32)h) << 16;
  return __builtin_bit_cast(float, u);
}

// Fragment-linear pre-split (same as R5/R9):
//  W: frag(kc 0..15, nb 0..15): elem(lane,j) = W[node=nb*16+(lane&15)][k=kc*32+(lane>>4)*8+j]
//     at linear ((kc*16+nb)*64+lane)*8+j
//  AT: frag(kc4 0..7, nb 0..3): elem(lane,j) = A[leaf=kc4*32+(lane>>4)*8+j][col=nb*16+(lane&15)]
//     at linear ((kc4*4+nb)*64+lane)*8+j
__global__ __launch_bounds__(256) void prep_kernel(
    const float* __restrict__ layers, const float* __restrict__ aprobs,
    u16* __restrict__ Wfh, u16* __restrict__ Wfl,
    u16* __restrict__ ATfh, u16* __restrict__ ATfl) {
  int id = blockIdx.x * 256 + threadIdx.x;
  if (id < 131072) {
    const int j = id & 7;
    const int lane = (id >> 3) & 63;
    const int nb = (id >> 9) & 15;
    const int kc = id >> 13;
    const int node = nb * 16 + (lane & 15);
    const int k = kc * 32 + ((lane >> 4) << 3) + j;
    const float v = (node < NODES) ? layers[node * IN_DIM + k] : 0.f;
    const u16 h = f32_bf16(v);
    Wfh[id] = h;
    Wfl[id] = f32_bf16(v - bf16_f32(h));
  } else if (id < 131072 + 16384) {
    const int t = id - 131072;
    const int j = t & 7;
    const int lane = (t >> 3) & 63;
    const int nb = (t >> 9) & 3;
    const int kc4 = t >> 11;
    const int c = nb * 16 + (lane & 15);
    const int leaf = kc4 * 32 + ((lane >> 4) << 3) + j;
    const float v = aprobs[leaf * ODIM + c];
    const u16 h = f32_bf16(v);
    ATfh[t] = h;
    ATfl[t] = f32_bf16(v - bf16_f32(h));
  }
}

// 512 threads (8 waves), BM=64 rows/block, grid 512, 2 blocks/CU.
// R13 delta vs R12: x staged as SINGLE bf16 (z = xh*wh + xh*wl, 2-term).
// Halves phase-1 A-LDS traffic, staging VALU, and cuts MFMA 48->32/wave/iter.
// LDS 64KB union: phase 1 x dbuf bf16 hi only (16KB); phase 2+ s_sig f32[64][256];
// phase 4 partials f32[64][64].
__global__ __launch_bounds__(512, 4) void prolo_main(
    const float* __restrict__ x, const float* __restrict__ comp,
    const float* __restrict__ alpha,
    const u16* __restrict__ Wfh, const u16* __restrict__ Wfl,
    const u16* __restrict__ ATfh, const u16* __restrict__ ATfl,
    float* __restrict__ out) {
  __shared__ __align__(16) unsigned char smem[65536];
  float* s_sig = (float*)smem;
  u16* sA = (u16*)smem;  // buf b at b*4096 (u16 units), 8 KB each

  const int tid = threadIdx.x;
  const int lane = tid & 63;
  const int w = tid >> 6;
  const int l15 = lane & 15;
  const int lq = lane >> 4;
  const int row0 = blockIdx.x * BM;
  const float alphav = alpha[0];

  // prefetch comparators for phase 2
  const int col0 = (w << 5) + l15;
  const int col1 = col0 + 16;
  const float cv0 = (col0 < NODES) ? comp[col0] : 0.f;
  const float cv1 = (col1 < NODES) ? comp[col1] : 0.f;

  // ---------- Phase 1: z GEMM. Wave w owns nodes [32w, 32w+32), all 64 rows.
  f32x4 acc[4][2];
#pragma unroll
  for (int i = 0; i < 4; ++i)
#pragma unroll
    for (int j = 0; j < 2; ++j) acc[i][j] = {0.f, 0.f, 0.f, 0.f};

  const int srow = tid >> 3;            // staging row 0..63
  const int k0 = (tid & 7) << 3;        // staging k 0..56
  const int soff = srow * 64 + (k0 ^ ((srow & 7) << 3));
  const float* xbase = x + (size_t)(row0 + srow) * IN_DIM + k0;

  // 2-deep register prefetch (chunk = 64 k-columns; 8 floats/thread)
  f32x4 vA0 = *reinterpret_cast<const f32x4*>(xbase);
  f32x4 vA1 = *reinterpret_cast<const f32x4*>(xbase + 4);
  f32x4 vB0 = *reinterpret_cast<const f32x4*>(xbase + 64);
  f32x4 vB1 = *reinterpret_cast<const f32x4*>(xbase + 68);

#define STAGE_CHUNK(P0, P1, BUF)                                              \
  {                                                                           \
    u32* dh = reinterpret_cast<u32*>(sA + (BUF)*4096 + soff);                 \
    float ff[8] = {P0[0], P0[1], P0[2], P0[3], P1[0], P1[1], P1[2], P1[3]};   \
    _Pragma("unroll") for (int j = 0; j < 4; ++j) {                           \
      u16 ha = f32_bf16(ff[2 * j]), hb = f32_bf16(ff[2 * j + 1]);             \
      dh[j] = (u32)ha | ((u32)hb << 16);                                      \
    }                                                                         \
  }

  const int wfbase = (w << 10) + (lane << 3);

  // W-fragment register double-buffer: set = 4 frags (one kq half).
  short8v wbhA[2], wblA[2], wbhB[2], wblB[2];

#define LOADW(WH, WL, KS, KQ)                                                 \
  {                                                                           \
    _Pragma("unroll") for (int ntl = 0; ntl < 2; ++ntl) {                     \
      const int fb = ((((KS) << 1) + (KQ)) << 13) + wfbase + (ntl << 9);      \
      WH[ntl] = *reinterpret_cast<const short8v*>(Wfh + fb);                  \
      WL[ntl] = *reinterpret_cast<const short8v*>(Wfl + fb);                  \
    }                                                                         \
  }

#define CHALF(WH, WL, KQ, BUF)                                                \
  {                                                                           \
    _Pragma("unroll") for (int mt = 0; mt < 4; ++mt) {                        \
      const int r = (mt << 4) + l15;                                          \
      const int kk = ((KQ) << 5) + (lq << 3);                                 \
      const int aoff = r * 64 + (kk ^ ((r & 7) << 3));                        \
      const short8v ah = *reinterpret_cast<const short8v*>(sA + (BUF)*4096 + aoff); \
      _Pragma("unroll") for (int ntl = 0; ntl < 2; ++ntl) {                   \
        acc[mt][ntl] = __builtin_amdgcn_mfma_f32_16x16x32_bf16(ah, WH[ntl], acc[mt][ntl], 0, 0, 0); \
        acc[mt][ntl] = __builtin_amdgcn_mfma_f32_16x16x32_bf16(ah, WL[ntl], acc[mt][ntl], 0, 0, 0); \
      }                                                                       \
    }                                                                         \
  }

  // prologue
  LOADW(wbhA, wblA, 0, 0);
  STAGE_CHUNK(vA0, vA1, 0);
  __syncthreads();

#pragma unroll
  for (int ks = 0; ks < 8; ++ks) {
    // x prefetch, 2 chunks ahead
    if (ks + 2 < 8) {
      const float* xp = xbase + (ks + 2) * 64;
      vA0 = *reinterpret_cast<const f32x4*>(xp);
      vA1 = *reinterpret_cast<const f32x4*>(xp + 4);
    }
    // issue W loads for this iter's second half before any compute
    LOADW(wbhB, wblB, ks, 1);
    // stage next x chunk (VALU + ds_write) — covers the W-load latency
    if (ks + 1 < 8) STAGE_CHUNK(vB0, vB1, ((ks + 1) & 1));

    // first half-compute (W prefetched last iter / prologue)
    CHALF(wbhA, wblA, 0, (ks & 1));
    // issue next iter's first-half W loads under the second half's MFMAs
    if (ks < 7) LOADW(wbhA, wblA, (ks + 1), 0);
    // second half-compute
    CHALF(wbhB, wblB, 1, (ks & 1));

    {
      f32x4 t0 = vA0, t1 = vA1;
      vA0 = vB0; vA1 = vB1;
      vB0 = t0;  vB1 = t1;
    }
    __syncthreads();
  }

  // ---------- Phase 2: sigmoid((z-c)*alpha) -> s_sig (col ^ (row&15) swizzle)
#pragma unroll
  for (int ntl = 0; ntl < 2; ++ntl) {
    const int col = (w << 5) + (ntl << 4) + l15;
    const float cv = ntl ? cv1 : cv0;
#pragma unroll
    for (int mt = 0; mt < 4; ++mt) {
#pragma unroll
      for (int r4 = 0; r4 < 4; ++r4) {
        const int r = (mt << 4) + (lq << 2) + r4;
        const float z = (acc[mt][ntl][r4] - cv) * alphav;
        const float s = 1.f / (1.f + __expf(-z));
        s_sig[(r << 8) + (col ^ (r & 15))] = s;
      }
    }
  }
  __syncthreads();

  // ---------- Phase 3+4: in-register leaf probs (single bf16) -> p@A MFMA.
  const int mt3 = w & 3;
  const int kh = w >> 2;
  const int arow = (mt3 << 4) + l15;
  const float* srow_p = s_sig + (arow << 8);
  const int sw = arow & 15;

  f32x4 acc2[4];
#pragma unroll
  for (int i = 0; i < 4; ++i) acc2[i] = {0.f, 0.f, 0.f, 0.f};

#pragma unroll
  for (int ks = 0; ks < 4; ++ks) {
    // hoist all 8 AT fragment loads — tree walk covers L2 latency
    short8v bhv[4], blv[4];
#pragma unroll
    for (int nt = 0; nt < 4; ++nt) {
      const int fb = ((((kh << 2) + ks) << 2) + nt) * 512 + (lane << 3);
      bhv[nt] = *reinterpret_cast<const short8v*>(ATfh + fb);
      blv[nt] = *reinterpret_cast<const short8v*>(ATfl + fb);
    }

    const int lb = (kh << 7) + (ks << 5) + (lq << 3);
    float P = 1.f;
#pragma unroll
    for (int n = 0; n < 5; ++n) {
      const int node = (1 << n) - 1 + (lb >> (8 - n));
      const float s = srow_p[node ^ sw];
      P *= ((lb >> (7 - n)) & 1) ? (1.f - s) : s;
    }
    const float s5 = srow_p[(31 + (lb >> 3)) ^ sw];
    const int n6 = 63 + (lb >> 2);
    const float s6a = srow_p[n6 ^ sw];
    const float s6b = srow_p[(n6 + 1) ^ sw];
    const int n7 = 127 + (lb >> 1);
    const float s7_0 = srow_p[n7 ^ sw];
    const float s7_1 = srow_p[(n7 + 1) ^ sw];
    const float s7_2 = srow_p[(n7 + 2) ^ sw];
    const float s7_3 = srow_p[(n7 + 3) ^ sw];
    const float q0 = P * s5, q1 = P - P * s5;
    const float r00 = q0 * s6a, r01 = q0 - q0 * s6a;
    const float r10 = q1 * s6b, r11 = q1 - q1 * s6b;
    float p[8];
    p[0] = r00 * s7_0; p[1] = r00 - p[0];
    p[2] = r01 * s7_1; p[3] = r01 - p[2];
    p[4] = r10 * s7_2; p[5] = r10 - p[4];
    p[6] = r11 * s7_3; p[7] = r11 - p[6];
    // single-bf16 p fragment
    short8v pah;
#pragma unroll
    for (int j = 0; j < 8; ++j) pah[j] = (short)f32_bf16(p[j]);
#pragma unroll
    for (int nt = 0; nt < 4; ++nt) {
      acc2[nt] = __builtin_amdgcn_mfma_f32_16x16x32_bf16(pah, bhv[nt], acc2[nt], 0, 0, 0);
      acc2[nt] = __builtin_amdgcn_mfma_f32_16x16x32_bf16(pah, blv[nt], acc2[nt], 0, 0, 0);
    }
  }
  __syncthreads();  // all waves done reading s_sig

  // K-half combine via smem partials (aliases s_sig, now dead)
  float* part = (float*)smem;  // [64][64] f32
  if (kh == 1) {
#pragma unroll
    for (int nt = 0; nt < 4; ++nt)
#pragma unroll
      for (int r4 = 0; r4 < 4; ++r4)
        part[(((mt3 << 4) + (lq << 2) + r4) << 6) + (nt << 4) + l15] = acc2[nt][r4];
  }
  __syncthreads();

  if (kh == 0) {
#pragma unroll
    for (int r4 = 0; r4 < 4; ++r4) {
      const int rloc = (mt3 << 4) + (lq << 2) + r4;
      float v0 = acc2[0][r4] + part[(rloc << 6) + l15];
      float v1 = acc2[1][r4] + part[(rloc << 6) + 16 + l15];
      float v2 = acc2[2][r4] + part[(rloc << 6) + 32 + l15];
      float v3 = acc2[3][r4] + part[(rloc << 6) + 48 + l15];
      float m = fmaxf(fmaxf(v0, v1), fmaxf(v2, v3));
#pragma unroll
      for (int d = 1; d < 16; d <<= 1) m = fmaxf(m, __shfl_xor(m, d, 64));
      float e0 = __expf(v0 - m), e1 = __expf(v1 - m), e2 = __expf(v2 - m), e3 = __expf(v3 - m);
      float ssum = e0 + e1 + e2 + e3;
#pragma unroll
      for (int d = 1; d < 16; d <<= 1) ssum += __shfl_xor(ssum, d, 64);
      const float inv = 1.f / ssum;
      float* op = out + (size_t)(row0 + rloc) * ODIM + l15;
      op[0] = e0 * inv;
      op[16] = e1 * inv;
      op[32] = e2 * inv;
      op[48] = e3 * inv;
    }
  }
}

extern "C" void kernel_launch(void* const* d_in, const int* in_sizes, int n_in,
                              void* d_out, int out_size, void* d_ws, size_t ws_size,
                              hipStream_t stream) {
  const float* x      = (const float*)d_in[0];
  const float* layers = (const float*)d_in[1];
  const float* comp   = (const float*)d_in[2];
  const float* alpha  = (const float*)d_in[3];
  const float* aprobs = (const float*)d_in[4];
  float* out = (float*)d_out;

  const size_t wsplit = (size_t)131072;
  const size_t atsz   = (size_t)16384;
  if (ws_size < (2 * wsplit + 2 * atsz) * sizeof(u16)) return;

  u16* Wfh  = (u16*)d_ws;
  u16* Wfl  = Wfh + wsplit;
  u16* ATfh = Wfl + wsplit;
  u16* ATfl = ATfh + atsz;

  const int prep_items = 131072 + 16384;
  prep_kernel<<<dim3((prep_items + 255) / 256), dim3(256), 0, stream>>>(
      layers, aprobs, Wfh, Wfl, ATfh, ATfl);

  prolo_main<<<dim3(32768 / BM), dim3(512), 0, stream>>>(
      x, comp, alpha, Wfh, Wfl, ATfh, ATfl, out);
}

// Round 14
// 32.074 us; speedup vs baseline: 1.5788x; 1.1929x over previous
//
#include <hip/hip_runtime.h>

#define NODES 255
#define IN_DIM 512
#define ODIM 64
#define BM 64

typedef __attribute__((ext_vector_type(8))) short short8v;
typedef __attribute__((ext_vector_type(4))) float f32x4;
typedef unsigned short u16;
typedef unsigned int u32;

__device__ __forceinline__ u16 f32_bf16(float f) {
  u32 u = __builtin_bit_cast(u32, f);
  u += 0x7FFFu + ((u >> 16) & 1u);
  return (u16)(u >> 16);
}
__device__ __forceinline__ float bf16_f32(u16 h) {
  u32 u = ((u32)h) << 16;
  return __builtin_bit_cast(float, u);
}

// Fragment-linear pre-pack, SINGLE bf16:
//  W': frag(kc 0..15, nb 0..15): elem(lane,j) = W[node=nb*16+(lane&15)][k=kc*32+(lane>>4)*8+j] - 0.5
//      (node 255 = all-ones row, so z'[.,255] = sum(x))
//      at linear ((kc*16+nb)*64+lane)*8+j
//  AT: frag(kc4 0..7, nb 0..3): elem(lane,j) = A[leaf=kc4*32+(lane>>4)*8+j][col=nb*16+(lane&15)]
//      at linear ((kc4*4+nb)*64+lane)*8+j
__global__ __launch_bounds__(256) void prep_kernel(
    const float* __restrict__ layers, const float* __restrict__ aprobs,
    u16* __restrict__ Wf, u16* __restrict__ ATf) {
  int id = blockIdx.x * 256 + threadIdx.x;
  if (id < 131072) {
    const int j = id & 7;
    const int lane = (id >> 3) & 63;
    const int nb = (id >> 9) & 15;
    const int kc = id >> 13;
    const int node = nb * 16 + (lane & 15);
    const int k = kc * 32 + ((lane >> 4) << 3) + j;
    const float v = (node < NODES) ? (layers[node * IN_DIM + k] - 0.5f) : 1.0f;
    Wf[id] = f32_bf16(v);
  } else if (id < 131072 + 16384) {
    const int t = id - 131072;
    const int j = t & 7;
    const int lane = (t >> 3) & 63;
    const int nb = (t >> 9) & 3;
    const int kc4 = t >> 11;
    const int c = nb * 16 + (lane & 15);
    const int leaf = kc4 * 32 + ((lane >> 4) << 3) + j;
    ATf[t] = f32_bf16(aprobs[leaf * ODIM + c]);
  }
}

// 512 threads (8 waves), BM=64 rows/block, grid 512, 2 blocks/CU.
// R14: W zero-shifted single bf16 + ones-row Sum(x) correction; AT single bf16.
// z[b,n] = z'[b,n] + 0.5*z'[b,255];  z' = xh @ W'^T  (1 MFMA term).
// LDS 64KB union + 256B: phase 1 x dbuf bf16 (16KB); phase 2+ s_sig f32[64][256];
// phase 4 partials f32[64][64]; z255s f32[64] at +65536.
__global__ __launch_bounds__(512, 4) void prolo_main(
    const float* __restrict__ x, const float* __restrict__ comp,
    const float* __restrict__ alpha,
    const u16* __restrict__ Wf, const u16* __restrict__ ATf,
    float* __restrict__ out) {
  __shared__ __align__(16) unsigned char smem[65536 + 256];
  float* s_sig = (float*)smem;
  u16* sA = (u16*)smem;               // buf b at b*4096 (u16 units), 8 KB each
  float* z255s = (float*)(smem + 65536);  // [64]

  const int tid = threadIdx.x;
  const int lane = tid & 63;
  const int w = tid >> 6;
  const int l15 = lane & 15;
  const int lq = lane >> 4;
  const int row0 = blockIdx.x * BM;
  const float alphav = alpha[0];

  // prefetch comparators for phase 2
  const int col0 = (w << 5) + l15;
  const int col1 = col0 + 16;
  const float cv0 = (col0 < NODES) ? comp[col0] : 0.f;
  const float cv1 = (col1 < NODES) ? comp[col1] : 0.f;

  // ---------- Phase 1: z' GEMM. Wave w owns nodes [32w, 32w+32), all 64 rows.
  f32x4 acc[4][2];
#pragma unroll
  for (int i = 0; i < 4; ++i)
#pragma unroll
    for (int j = 0; j < 2; ++j) acc[i][j] = {0.f, 0.f, 0.f, 0.f};

  const int srow = tid >> 3;            // staging row 0..63
  const int k0 = (tid & 7) << 3;        // staging k 0..56
  const int soff = srow * 64 + (k0 ^ ((srow & 7) << 3));
  const float* xbase = x + (size_t)(row0 + srow) * IN_DIM + k0;

  // 2-deep register prefetch (chunk = 64 k-columns; 8 floats/thread)
  f32x4 vA0 = *reinterpret_cast<const f32x4*>(xbase);
  f32x4 vA1 = *reinterpret_cast<const f32x4*>(xbase + 4);
  f32x4 vB0 = *reinterpret_cast<const f32x4*>(xbase + 64);
  f32x4 vB1 = *reinterpret_cast<const f32x4*>(xbase + 68);

#define STAGE_CHUNK(P0, P1, BUF)                                              \
  {                                                                           \
    u32* dh = reinterpret_cast<u32*>(sA + (BUF)*4096 + soff);                 \
    float ff[8] = {P0[0], P0[1], P0[2], P0[3], P1[0], P1[1], P1[2], P1[3]};   \
    _Pragma("unroll") for (int j = 0; j < 4; ++j) {                           \
      u16 ha = f32_bf16(ff[2 * j]), hb = f32_bf16(ff[2 * j + 1]);             \
      dh[j] = (u32)ha | ((u32)hb << 16);                                      \
    }                                                                         \
  }

  const int wfbase = (w << 10) + (lane << 3);

  // W-fragment register double-buffer: set = 2 frags (one kq half).
  short8v wA[2], wB[2];

#define LOADW(WD, KS, KQ)                                                     \
  {                                                                           \
    _Pragma("unroll") for (int ntl = 0; ntl < 2; ++ntl) {                     \
      const int fb = ((((KS) << 1) + (KQ)) << 13) + wfbase + (ntl << 9);      \
      WD[ntl] = *reinterpret_cast<const short8v*>(Wf + fb);                   \
    }                                                                         \
  }

#define CHALF(WD, KQ, BUF)                                                    \
  {                                                                           \
    _Pragma("unroll") for (int mt = 0; mt < 4; ++mt) {                        \
      const int r = (mt << 4) + l15;                                          \
      const int kk = ((KQ) << 5) + (lq << 3);                                 \
      const int aoff = r * 64 + (kk ^ ((r & 7) << 3));                        \
      const short8v ah = *reinterpret_cast<const short8v*>(sA + (BUF)*4096 + aoff); \
      _Pragma("unroll") for (int ntl = 0; ntl < 2; ++ntl) {                   \
        acc[mt][ntl] = __builtin_amdgcn_mfma_f32_16x16x32_bf16(ah, WD[ntl], acc[mt][ntl], 0, 0, 0); \
      }                                                                       \
    }                                                                         \
  }

  // prologue
  LOADW(wA, 0, 0);
  STAGE_CHUNK(vA0, vA1, 0);
  __syncthreads();

#pragma unroll
  for (int ks = 0; ks < 8; ++ks) {
    // x prefetch, 2 chunks ahead
    if (ks + 2 < 8) {
      const float* xp = xbase + (ks + 2) * 64;
      vA0 = *reinterpret_cast<const f32x4*>(xp);
      vA1 = *reinterpret_cast<const f32x4*>(xp + 4);
    }
    // issue W loads for this iter's second half before any compute
    LOADW(wB, ks, 1);
    // stage next x chunk (VALU + ds_write) — covers the W-load latency
    if (ks + 1 < 8) STAGE_CHUNK(vB0, vB1, ((ks + 1) & 1));

    // first half-compute
    CHALF(wA, 0, (ks & 1));
    // issue next iter's first-half W loads under the second half's MFMAs
    if (ks < 7) LOADW(wA, (ks + 1), 0);
    // second half-compute
    CHALF(wB, 1, (ks & 1));

    {
      f32x4 t0 = vA0, t1 = vA1;
      vA0 = vB0; vA1 = vB1;
      vB0 = t0;  vB1 = t1;
    }
    __syncthreads();
  }

  // ---------- Phase 1b: wave 7 publishes z'[row][255] = sum(x_row) (ones column)
  if (w == 7 && l15 == 15) {
#pragma unroll
    for (int mt = 0; mt < 4; ++mt)
#pragma unroll
      for (int r4 = 0; r4 < 4; ++r4)
        z255s[(mt << 4) + (lq << 2) + r4] = acc[mt][1][r4];
  }
  __syncthreads();

  // ---------- Phase 2: sigmoid((z' + 0.5*z255 - c)*alpha) -> s_sig (col ^ (row&15))
#pragma unroll
  for (int ntl = 0; ntl < 2; ++ntl) {
    const int col = (w << 5) + (ntl << 4) + l15;
    const float cv = ntl ? cv1 : cv0;
#pragma unroll
    for (int mt = 0; mt < 4; ++mt) {
#pragma unroll
      for (int r4 = 0; r4 < 4; ++r4) {
        const int r = (mt << 4) + (lq << 2) + r4;
        const float z = (acc[mt][ntl][r4] + 0.5f * z255s[r] - cv) * alphav;
        const float s = 1.f / (1.f + __expf(-z));
        s_sig[(r << 8) + (col ^ (r & 15))] = s;
      }
    }
  }
  __syncthreads();

  // ---------- Phase 3+4: in-register leaf probs (single bf16) -> p@A MFMA (single AT).
  const int mt3 = w & 3;
  const int kh = w >> 2;
  const int arow = (mt3 << 4) + l15;
  const float* srow_p = s_sig + (arow << 8);
  const int sw = arow & 15;

  f32x4 acc2[4];
#pragma unroll
  for (int i = 0; i < 4; ++i) acc2[i] = {0.f, 0.f, 0.f, 0.f};

#pragma unroll
  for (int ks = 0; ks < 4; ++ks) {
    // hoist all 4 AT fragment loads — tree walk covers L2 latency
    short8v bhv[4];
#pragma unroll
    for (int nt = 0; nt < 4; ++nt) {
      const int fb = ((((kh << 2) + ks) << 2) + nt) * 512 + (lane << 3);
      bhv[nt] = *reinterpret_cast<const short8v*>(ATf + fb);
    }

    const int lb = (kh << 7) + (ks << 5) + (lq << 3);
    float P = 1.f;
#pragma unroll
    for (int n = 0; n < 5; ++n) {
      const int node = (1 << n) - 1 + (lb >> (8 - n));
      const float s = srow_p[node ^ sw];
      P *= ((lb >> (7 - n)) & 1) ? (1.f - s) : s;
    }
    const float s5 = srow_p[(31 + (lb >> 3)) ^ sw];
    const int n6 = 63 + (lb >> 2);
    const float s6a = srow_p[n6 ^ sw];
    const float s6b = srow_p[(n6 + 1) ^ sw];
    const int n7 = 127 + (lb >> 1);
    const float s7_0 = srow_p[n7 ^ sw];
    const float s7_1 = srow_p[(n7 + 1) ^ sw];
    const float s7_2 = srow_p[(n7 + 2) ^ sw];
    const float s7_3 = srow_p[(n7 + 3) ^ sw];
    const float q0 = P * s5, q1 = P - P * s5;
    const float r00 = q0 * s6a, r01 = q0 - q0 * s6a;
    const float r10 = q1 * s6b, r11 = q1 - q1 * s6b;
    float p[8];
    p[0] = r00 * s7_0; p[1] = r00 - p[0];
    p[2] = r01 * s7_1; p[3] = r01 - p[2];
    p[4] = r10 * s7_2; p[5] = r10 - p[4];
    p[6] = r11 * s7_3; p[7] = r11 - p[6];
    // single-bf16 p fragment
    short8v pah;
#pragma unroll
    for (int j = 0; j < 8; ++j) pah[j] = (short)f32_bf16(p[j]);
#pragma unroll
    for (int nt = 0; nt < 4; ++nt)
      acc2[nt] = __builtin_amdgcn_mfma_f32_16x16x32_bf16(pah, bhv[nt], acc2[nt], 0, 0, 0);
  }
  __syncthreads();  // all waves done reading s_sig

  // K-half combine via smem partials (aliases s_sig, now dead)
  float* part = (float*)smem;  // [64][64] f32
  if (kh == 1) {
#pragma unroll
    for (int nt = 0; nt < 4; ++nt)
#pragma unroll
      for (int r4 = 0; r4 < 4; ++r4)
        part[(((mt3 << 4) + (lq << 2) + r4) << 6) + (nt << 4) + l15] = acc2[nt][r4];
  }
  __syncthreads();

  if (kh == 0) {
#pragma unroll
    for (int r4 = 0; r4 < 4; ++r4) {
      const int rloc = (mt3 << 4) + (lq << 2) + r4;
      float v0 = acc2[0][r4] + part[(rloc << 6) + l15];
      float v1 = acc2[1][r4] + part[(rloc << 6) + 16 + l15];
      float v2 = acc2[2][r4] + part[(rloc << 6) + 32 + l15];
      float v3 = acc2[3][r4] + part[(rloc << 6) + 48 + l15];
      float m = fmaxf(fmaxf(v0, v1), fmaxf(v2, v3));
#pragma unroll
      for (int d = 1; d < 16; d <<= 1) m = fmaxf(m, __shfl_xor(m, d, 64));
      float e0 = __expf(v0 - m), e1 = __expf(v1 - m), e2 = __expf(v2 - m), e3 = __expf(v3 - m);
      float ssum = e0 + e1 + e2 + e3;
#pragma unroll
      for (int d = 1; d < 16; d <<= 1) ssum += __shfl_xor(ssum, d, 64);
      const float inv = 1.f / ssum;
      float* op = out + (size_t)(row0 + rloc) * ODIM + l15;
      op[0] = e0 * inv;
      op[16] = e1 * inv;
      op[32] = e2 * inv;
      op[48] = e3 * inv;
    }
  }
}

extern "C" void kernel_launch(void* const* d_in, const int* in_sizes, int n_in,
                              void* d_out, int out_size, void* d_ws, size_t ws_size,
                              hipStream_t stream) {
  const float* x      = (const float*)d_in[0];
  const float* layers = (const float*)d_in[1];
  const float* comp   = (const float*)d_in[2];
  const float* alpha  = (const float*)d_in[3];
  const float* aprobs = (const float*)d_in[4];
  float* out = (float*)d_out;

  const size_t wsz  = (size_t)131072;
  const size_t atsz = (size_t)16384;
  if (ws_size < (wsz + atsz) * sizeof(u16)) return;

  u16* Wf  = (u16*)d_ws;
  u16* ATf = Wf + wsz;

  const int prep_items = 131072 + 16384;
  prep_kernel<<<dim3((prep_items + 255) / 256), dim3(256), 0, stream>>>(
      layers, aprobs, Wf, ATf);

  prolo_main<<<dim3(32768 / BM), dim3(512), 0, stream>>>(
      x, comp, alpha, Wf, ATf, out);
}

// Round 15
// 31.187 us; speedup vs baseline: 1.6237x; 1.0284x over previous
//
#include <hip/hip_runtime.h>

#define NODES 255
#define IN_DIM 512
#define ODIM 64
#define BM 64

typedef __attribute__((ext_vector_type(8))) short short8v;
typedef __attribute__((ext_vector_type(4))) float f32x4;
typedef unsigned short u16;
typedef unsigned int u32;

__device__ __forceinline__ u16 f32_bf16(float f) {
  u32 u = __builtin_bit_cast(u32, f);
  u += 0x7FFFu + ((u >> 16) & 1u);
  return (u16)(u >> 16);
}
__device__ __forceinline__ float bf16_f32(u16 h) {
  u32 u = ((u32)h) << 16;
  return __builtin_bit_cast(float, u);
}

// Fragment-linear pre-pack, SINGLE bf16 (same as R14):
//  W': frag(kc 0..15, nb 0..15): elem(lane,j) = W[node=nb*16+(lane&15)][k=kc*32+(lane>>4)*8+j] - 0.5
//      (node 255 = all-ones row, so z'[.,255] = sum(x))
//  AT: frag(kc4 0..7, nb 0..3): elem(lane,j) = A[leaf=kc4*32+(lane>>4)*8+j][col=nb*16+(lane&15)]
__global__ __launch_bounds__(256) void prep_kernel(
    const float* __restrict__ layers, const float* __restrict__ aprobs,
    u16* __restrict__ Wf, u16* __restrict__ ATf) {
  int id = blockIdx.x * 256 + threadIdx.x;
  if (id < 131072) {
    const int j = id & 7;
    const int lane = (id >> 3) & 63;
    const int nb = (id >> 9) & 15;
    const int kc = id >> 13;
    const int node = nb * 16 + (lane & 15);
    const int k = kc * 32 + ((lane >> 4) << 3) + j;
    const float v = (node < NODES) ? (layers[node * IN_DIM + k] - 0.5f) : 1.0f;
    Wf[id] = f32_bf16(v);
  } else if (id < 131072 + 16384) {
    const int t = id - 131072;
    const int j = t & 7;
    const int lane = (t >> 3) & 63;
    const int nb = (t >> 9) & 3;
    const int kc4 = t >> 11;
    const int c = nb * 16 + (lane & 15);
    const int leaf = kc4 * 32 + ((lane >> 4) << 3) + j;
    ATf[t] = f32_bf16(aprobs[leaf * ODIM + c]);
  }
}

// 512 threads (8 waves), BM=64 rows/block, grid 512, 2 blocks/CU.
// R15 vs R14: vectorized all-wave epilogue (part[2][64][68], dwordx4 stores),
// tree-walk level-0..2 hoisting. Phase 1/2 byte-identical to R14.
__global__ __launch_bounds__(512, 4) void prolo_main(
    const float* __restrict__ x, const float* __restrict__ comp,
    const float* __restrict__ alpha,
    const u16* __restrict__ Wf, const u16* __restrict__ ATf,
    float* __restrict__ out) {
  __shared__ __align__(16) unsigned char smem[65536 + 256];
  float* s_sig = (float*)smem;
  u16* sA = (u16*)smem;               // buf b at b*4096 (u16 units), 8 KB each
  float* part = (float*)smem;         // [2][64][68] f32 = 34,816 B (after phase 3)
  float* z255s = (float*)(smem + 65536);  // [64]

  const int tid = threadIdx.x;
  const int lane = tid & 63;
  const int w = tid >> 6;
  const int l15 = lane & 15;
  const int lq = lane >> 4;
  const int row0 = blockIdx.x * BM;
  const float alphav = alpha[0];

  // prefetch comparators for phase 2
  const int col0 = (w << 5) + l15;
  const int col1 = col0 + 16;
  const float cv0 = (col0 < NODES) ? comp[col0] : 0.f;
  const float cv1 = (col1 < NODES) ? comp[col1] : 0.f;

  // ---------- Phase 1: z' GEMM. Wave w owns nodes [32w, 32w+32), all 64 rows.
  f32x4 acc[4][2];
#pragma unroll
  for (int i = 0; i < 4; ++i)
#pragma unroll
    for (int j = 0; j < 2; ++j) acc[i][j] = {0.f, 0.f, 0.f, 0.f};

  const int srow = tid >> 3;            // staging row 0..63
  const int k0 = (tid & 7) << 3;        // staging k 0..56
  const int soff = srow * 64 + (k0 ^ ((srow & 7) << 3));
  const float* xbase = x + (size_t)(row0 + srow) * IN_DIM + k0;

  // 2-deep register prefetch (chunk = 64 k-columns; 8 floats/thread)
  f32x4 vA0 = *reinterpret_cast<const f32x4*>(xbase);
  f32x4 vA1 = *reinterpret_cast<const f32x4*>(xbase + 4);
  f32x4 vB0 = *reinterpret_cast<const f32x4*>(xbase + 64);
  f32x4 vB1 = *reinterpret_cast<const f32x4*>(xbase + 68);

#define STAGE_CHUNK(P0, P1, BUF)                                              \
  {                                                                           \
    u32* dh = reinterpret_cast<u32*>(sA + (BUF)*4096 + soff);                 \
    float ff[8] = {P0[0], P0[1], P0[2], P0[3], P1[0], P1[1], P1[2], P1[3]};   \
    _Pragma("unroll") for (int j = 0; j < 4; ++j) {                           \
      u16 ha = f32_bf16(ff[2 * j]), hb = f32_bf16(ff[2 * j + 1]);             \
      dh[j] = (u32)ha | ((u32)hb << 16);                                      \
    }                                                                         \
  }

  const int wfbase = (w << 10) + (lane << 3);

  short8v wA[2], wB[2];

#define LOADW(WD, KS, KQ)                                                     \
  {                                                                           \
    _Pragma("unroll") for (int ntl = 0; ntl < 2; ++ntl) {                     \
      const int fb = ((((KS) << 1) + (KQ)) << 13) + wfbase + (ntl << 9);      \
      WD[ntl] = *reinterpret_cast<const short8v*>(Wf + fb);                   \
    }                                                                         \
  }

#define CHALF(WD, KQ, BUF)                                                    \
  {                                                                           \
    _Pragma("unroll") for (int mt = 0; mt < 4; ++mt) {                        \
      const int r = (mt << 4) + l15;                                          \
      const int kk = ((KQ) << 5) + (lq << 3);                                 \
      const int aoff = r * 64 + (kk ^ ((r & 7) << 3));                        \
      const short8v ah = *reinterpret_cast<const short8v*>(sA + (BUF)*4096 + aoff); \
      _Pragma("unroll") for (int ntl = 0; ntl < 2; ++ntl) {                   \
        acc[mt][ntl] = __builtin_amdgcn_mfma_f32_16x16x32_bf16(ah, WD[ntl], acc[mt][ntl], 0, 0, 0); \
      }                                                                       \
    }                                                                         \
  }

  // prologue
  LOADW(wA, 0, 0);
  STAGE_CHUNK(vA0, vA1, 0);
  __syncthreads();

#pragma unroll
  for (int ks = 0; ks < 8; ++ks) {
    if (ks + 2 < 8) {
      const float* xp = xbase + (ks + 2) * 64;
      vA0 = *reinterpret_cast<const f32x4*>(xp);
      vA1 = *reinterpret_cast<const f32x4*>(xp + 4);
    }
    LOADW(wB, ks, 1);
    if (ks + 1 < 8) STAGE_CHUNK(vB0, vB1, ((ks + 1) & 1));

    CHALF(wA, 0, (ks & 1));
    if (ks < 7) LOADW(wA, (ks + 1), 0);
    CHALF(wB, 1, (ks & 1));

    {
      f32x4 t0 = vA0, t1 = vA1;
      vA0 = vB0; vA1 = vB1;
      vB0 = t0;  vB1 = t1;
    }
    __syncthreads();
  }

  // ---------- Phase 1b: wave 7 publishes z'[row][255] = sum(x_row) (ones column)
  if (w == 7 && l15 == 15) {
#pragma unroll
    for (int mt = 0; mt < 4; ++mt)
#pragma unroll
      for (int r4 = 0; r4 < 4; ++r4)
        z255s[(mt << 4) + (lq << 2) + r4] = acc[mt][1][r4];
  }
  __syncthreads();

  // ---------- Phase 2: sigmoid((z' + 0.5*z255 - c)*alpha) -> s_sig (col ^ (row&15))
#pragma unroll
  for (int ntl = 0; ntl < 2; ++ntl) {
    const int col = (w << 5) + (ntl << 4) + l15;
    const float cv = ntl ? cv1 : cv0;
#pragma unroll
    for (int mt = 0; mt < 4; ++mt) {
#pragma unroll
      for (int r4 = 0; r4 < 4; ++r4) {
        const int r = (mt << 4) + (lq << 2) + r4;
        const float z = (acc[mt][ntl][r4] + 0.5f * z255s[r] - cv) * alphav;
        const float s = 1.f / (1.f + __expf(-z));
        s_sig[(r << 8) + (col ^ (r & 15))] = s;
      }
    }
  }
  __syncthreads();

  // ---------- Phase 3+4: in-register leaf probs (single bf16) -> p@A MFMA.
  const int mt3 = w & 3;
  const int kh = w >> 2;
  const int arow = (mt3 << 4) + l15;
  const float* srow_p = s_sig + (arow << 8);
  const int sw = arow & 15;

  // hoisted tree levels 0..2 (constant across the ks loop for fixed kh)
  const float s0v = srow_p[0 ^ sw];
  const float s1v = srow_p[(1 + kh) ^ sw];
  const float f0 = kh ? (1.f - s0v) : s0v;
  const float pre01_0 = f0 * s1v;
  const float pre01_1 = f0 - f0 * s1v;
  const int n2b_ = 3 + (kh << 1);
  const float s2a = srow_p[n2b_ ^ sw];
  const float s2b = srow_p[(n2b_ + 1) ^ sw];

  f32x4 acc2[4];
#pragma unroll
  for (int i = 0; i < 4; ++i) acc2[i] = {0.f, 0.f, 0.f, 0.f};

#pragma unroll
  for (int ks = 0; ks < 4; ++ks) {
    // hoist AT fragment loads — tree walk covers L2 latency
    short8v bhv[4];
#pragma unroll
    for (int nt = 0; nt < 4; ++nt) {
      const int fb = ((((kh << 2) + ks) << 2) + nt) * 512 + (lane << 3);
      bhv[nt] = *reinterpret_cast<const short8v*>(ATf + fb);
    }

    const int lb = (kh << 7) + (ks << 5) + (lq << 3);
    // levels 0-2 from hoisted values
    const float pre01 = (ks & 2) ? pre01_1 : pre01_0;
    const float s2 = (ks & 2) ? s2b : s2a;
    float P = pre01 * ((ks & 1) ? (1.f - s2) : s2);
    // level 3: node 7+4kh+ks, dir = lq>>1
    const float s3 = srow_p[(7 + (kh << 2) + ks) ^ sw];
    P *= (lq >> 1) ? (1.f - s3) : s3;
    // level 4: node 15+8kh+2ks+(lq>>1), dir = lq&1
    const float s4 = srow_p[(15 + (kh << 3) + (ks << 1) + (lq >> 1)) ^ sw];
    P *= (lq & 1) ? (1.f - s4) : s4;
    // levels 5-7 per 8-leaf chunk
    const float s5 = srow_p[(31 + (lb >> 3)) ^ sw];
    const int n6 = 63 + (lb >> 2);
    const float s6a = srow_p[n6 ^ sw];
    const float s6b = srow_p[(n6 + 1) ^ sw];
    const int n7 = 127 + (lb >> 1);
    const float s7_0 = srow_p[n7 ^ sw];
    const float s7_1 = srow_p[(n7 + 1) ^ sw];
    const float s7_2 = srow_p[(n7 + 2) ^ sw];
    const float s7_3 = srow_p[(n7 + 3) ^ sw];
    const float q0 = P * s5, q1 = P - P * s5;
    const float r00 = q0 * s6a, r01 = q0 - q0 * s6a;
    const float r10 = q1 * s6b, r11 = q1 - q1 * s6b;
    float p[8];
    p[0] = r00 * s7_0; p[1] = r00 - p[0];
    p[2] = r01 * s7_1; p[3] = r01 - p[2];
    p[4] = r10 * s7_2; p[5] = r10 - p[4];
    p[6] = r11 * s7_3; p[7] = r11 - p[6];
    short8v pah;
#pragma unroll
    for (int j = 0; j < 8; ++j) pah[j] = (short)f32_bf16(p[j]);
#pragma unroll
    for (int nt = 0; nt < 4; ++nt)
      acc2[nt] = __builtin_amdgcn_mfma_f32_16x16x32_bf16(pah, bhv[nt], acc2[nt], 0, 0, 0);
  }
  __syncthreads();  // all waves done reading s_sig

  // ---------- Phase 4b: ALL waves write partials to part[kh][64][68]
#pragma unroll
  for (int nt = 0; nt < 4; ++nt)
#pragma unroll
    for (int r4 = 0; r4 < 4; ++r4)
      part[(kh * 64 + (mt3 << 4) + (lq << 2) + r4) * 68 + (nt << 4) + l15] = acc2[nt][r4];
  __syncthreads();

  // ---------- Phase 5: vectorized reduce + softmax + dwordx4 stores.
  // Thread t: row r = t>>3, col group g = t&7 (cols 8g..8g+7).
  {
    const int r = tid >> 3;
    const int g = tid & 7;
    const float* p0 = part + (r * 68) + (g << 3);
    const float* p1 = part + ((64 + r) * 68) + (g << 3);
    f32x4 a0 = *reinterpret_cast<const f32x4*>(p0);
    f32x4 a1 = *reinterpret_cast<const f32x4*>(p0 + 4);
    f32x4 b0 = *reinterpret_cast<const f32x4*>(p1);
    f32x4 b1 = *reinterpret_cast<const f32x4*>(p1 + 4);
    float v[8];
#pragma unroll
    for (int i = 0; i < 4; ++i) { v[i] = a0[i] + b0[i]; v[4 + i] = a1[i] + b1[i]; }
    float m = v[0];
#pragma unroll
    for (int i = 1; i < 8; ++i) m = fmaxf(m, v[i]);
#pragma unroll
    for (int d = 1; d < 8; d <<= 1) m = fmaxf(m, __shfl_xor(m, d, 64));
    float e[8];
    float ssum = 0.f;
#pragma unroll
    for (int i = 0; i < 8; ++i) { e[i] = __expf(v[i] - m); ssum += e[i]; }
#pragma unroll
    for (int d = 1; d < 8; d <<= 1) ssum += __shfl_xor(ssum, d, 64);
    const float inv = 1.f / ssum;
    f32x4 o0, o1;
#pragma unroll
    for (int i = 0; i < 4; ++i) { o0[i] = e[i] * inv; o1[i] = e[4 + i] * inv; }
    float* op = out + (size_t)(row0 + r) * ODIM + (g << 3);
    *reinterpret_cast<f32x4*>(op) = o0;
    *reinterpret_cast<f32x4*>(op + 4) = o1;
  }
}

extern "C" void kernel_launch(void* const* d_in, const int* in_sizes, int n_in,
                              void* d_out, int out_size, void* d_ws, size_t ws_size,
                              hipStream_t stream) {
  const float* x      = (const float*)d_in[0];
  const float* layers = (const float*)d_in[1];
  const float* comp   = (const float*)d_in[2];
  const float* alpha  = (const float*)d_in[3];
  const float* aprobs = (const float*)d_in[4];
  float* out = (float*)d_out;

  const size_t wsz  = (size_t)131072;
  const size_t atsz = (size_t)16384;
  if (ws_size < (wsz + atsz) * sizeof(u16)) return;

  u16* Wf  = (u16*)d_ws;
  u16* ATf = Wf + wsz;

  const int prep_items = 131072 + 16384;
  prep_kernel<<<dim3((prep_items + 255) / 256), dim3(256), 0, stream>>>(
      layers, aprobs, Wf, ATf);

  prolo_main<<<dim3(32768 / BM), dim3(512), 0, stream>>>(
      x, comp, alpha, Wf, ATf, out);
}

// Round 16
// 30.869 us; speedup vs baseline: 1.6404x; 1.0103x over previous
//
#include <hip/hip_runtime.h>

#define NODES 255
#define IN_DIM 512
#define ODIM 64
#define BM 64

typedef __attribute__((ext_vector_type(8))) short short8v;
typedef __attribute__((ext_vector_type(4))) float f32x4;
typedef __attribute__((ext_vector_type(4))) unsigned int u32x4;
typedef unsigned short u16;
typedef unsigned int u32;

__device__ __forceinline__ u16 f32_bf16(float f) {
  u32 u = __builtin_bit_cast(u32, f);
  u += 0x7FFFu + ((u >> 16) & 1u);
  return (u16)(u >> 16);
}
__device__ __forceinline__ float bf16_f32(u16 h) {
  u32 u = ((u32)h) << 16;
  return __builtin_bit_cast(float, u);
}
// packed RNE f32x2 -> bf16x2 in one VALU instr (gfx950)
__device__ __forceinline__ u32 cvt_pk_bf16(float lo, float hi) {
  u32 r;
  asm("v_cvt_pk_bf16_f32 %0, %1, %2" : "=v"(r) : "v"(lo), "v"(hi));
  return r;
}

// Fragment-linear pre-pack, SINGLE bf16 (same as R14/R15):
//  W': frag(kc 0..15, nb 0..15): elem(lane,j) = W[node=nb*16+(lane&15)][k=kc*32+(lane>>4)*8+j] - 0.5
//      (node 255 = all-ones row, so z'[.,255] = sum(x))
//  AT: frag(kc4 0..7, nb 0..3): elem(lane,j) = A[leaf=kc4*32+(lane>>4)*8+j][col=nb*16+(lane&15)]
__global__ __launch_bounds__(256) void prep_kernel(
    const float* __restrict__ layers, const float* __restrict__ aprobs,
    u16* __restrict__ Wf, u16* __restrict__ ATf) {
  int id = blockIdx.x * 256 + threadIdx.x;
  if (id < 131072) {
    const int j = id & 7;
    const int lane = (id >> 3) & 63;
    const int nb = (id >> 9) & 15;
    const int kc = id >> 13;
    const int node = nb * 16 + (lane & 15);
    const int k = kc * 32 + ((lane >> 4) << 3) + j;
    const float v = (node < NODES) ? (layers[node * IN_DIM + k] - 0.5f) : 1.0f;
    Wf[id] = f32_bf16(v);
  } else if (id < 131072 + 16384) {
    const int t = id - 131072;
    const int j = t & 7;
    const int lane = (t >> 3) & 63;
    const int nb = (t >> 9) & 3;
    const int kc4 = t >> 11;
    const int c = nb * 16 + (lane & 15);
    const int leaf = kc4 * 32 + ((lane >> 4) << 3) + j;
    ATf[t] = f32_bf16(aprobs[leaf * ODIM + c]);
  }
}

// 512 threads (8 waves), BM=64 rows/block, grid 512, 2 blocks/CU.
// R16 vs R15: v_cvt_pk_bf16_f32 for the x-staging and p-fragment conversions
// (compiler can't derive it from the integer-RNE form). All else identical.
__global__ __launch_bounds__(512, 4) void prolo_main(
    const float* __restrict__ x, const float* __restrict__ comp,
    const float* __restrict__ alpha,
    const u16* __restrict__ Wf, const u16* __restrict__ ATf,
    float* __restrict__ out) {
  __shared__ __align__(16) unsigned char smem[65536 + 256];
  float* s_sig = (float*)smem;
  u16* sA = (u16*)smem;               // buf b at b*4096 (u16 units), 8 KB each
  float* part = (float*)smem;         // [2][64][68] f32 (after phase 3)
  float* z255s = (float*)(smem + 65536);  // [64]

  const int tid = threadIdx.x;
  const int lane = tid & 63;
  const int w = tid >> 6;
  const int l15 = lane & 15;
  const int lq = lane >> 4;
  const int row0 = blockIdx.x * BM;
  const float alphav = alpha[0];

  // prefetch comparators for phase 2
  const int col0 = (w << 5) + l15;
  const int col1 = col0 + 16;
  const float cv0 = (col0 < NODES) ? comp[col0] : 0.f;
  const float cv1 = (col1 < NODES) ? comp[col1] : 0.f;

  // ---------- Phase 1: z' GEMM. Wave w owns nodes [32w, 32w+32), all 64 rows.
  f32x4 acc[4][2];
#pragma unroll
  for (int i = 0; i < 4; ++i)
#pragma unroll
    for (int j = 0; j < 2; ++j) acc[i][j] = {0.f, 0.f, 0.f, 0.f};

  const int srow = tid >> 3;            // staging row 0..63
  const int k0 = (tid & 7) << 3;        // staging k 0..56
  const int soff = srow * 64 + (k0 ^ ((srow & 7) << 3));
  const float* xbase = x + (size_t)(row0 + srow) * IN_DIM + k0;

  // 2-deep register prefetch (chunk = 64 k-columns; 8 floats/thread)
  f32x4 vA0 = *reinterpret_cast<const f32x4*>(xbase);
  f32x4 vA1 = *reinterpret_cast<const f32x4*>(xbase + 4);
  f32x4 vB0 = *reinterpret_cast<const f32x4*>(xbase + 64);
  f32x4 vB1 = *reinterpret_cast<const f32x4*>(xbase + 68);

#define STAGE_CHUNK(P0, P1, BUF)                                              \
  {                                                                           \
    u32* dh = reinterpret_cast<u32*>(sA + (BUF)*4096 + soff);                 \
    dh[0] = cvt_pk_bf16(P0[0], P0[1]);                                        \
    dh[1] = cvt_pk_bf16(P0[2], P0[3]);                                        \
    dh[2] = cvt_pk_bf16(P1[0], P1[1]);                                        \
    dh[3] = cvt_pk_bf16(P1[2], P1[3]);                                        \
  }

  const int wfbase = (w << 10) + (lane << 3);

  short8v wA[2], wB[2];

#define LOADW(WD, KS, KQ)                                                     \
  {                                                                           \
    _Pragma("unroll") for (int ntl = 0; ntl < 2; ++ntl) {                     \
      const int fb = ((((KS) << 1) + (KQ)) << 13) + wfbase + (ntl << 9);      \
      WD[ntl] = *reinterpret_cast<const short8v*>(Wf + fb);                   \
    }                                                                         \
  }

#define CHALF(WD, KQ, BUF)                                                    \
  {                                                                           \
    _Pragma("unroll") for (int mt = 0; mt < 4; ++mt) {                        \
      const int r = (mt << 4) + l15;                                          \
      const int kk = ((KQ) << 5) + (lq << 3);                                 \
      const int aoff = r * 64 + (kk ^ ((r & 7) << 3));                        \
      const short8v ah = *reinterpret_cast<const short8v*>(sA + (BUF)*4096 + aoff); \
      _Pragma("unroll") for (int ntl = 0; ntl < 2; ++ntl) {                   \
        acc[mt][ntl] = __builtin_amdgcn_mfma_f32_16x16x32_bf16(ah, WD[ntl], acc[mt][ntl], 0, 0, 0); \
      }                                                                       \
    }                                                                         \
  }

  // prologue
  LOADW(wA, 0, 0);
  STAGE_CHUNK(vA0, vA1, 0);
  __syncthreads();

#pragma unroll
  for (int ks = 0; ks < 8; ++ks) {
    if (ks + 2 < 8) {
      const float* xp = xbase + (ks + 2) * 64;
      vA0 = *reinterpret_cast<const f32x4*>(xp);
      vA1 = *reinterpret_cast<const f32x4*>(xp + 4);
    }
    LOADW(wB, ks, 1);
    if (ks + 1 < 8) STAGE_CHUNK(vB0, vB1, ((ks + 1) & 1));

    CHALF(wA, 0, (ks & 1));
    if (ks < 7) LOADW(wA, (ks + 1), 0);
    CHALF(wB, 1, (ks & 1));

    {
      f32x4 t0 = vA0, t1 = vA1;
      vA0 = vB0; vA1 = vB1;
      vB0 = t0;  vB1 = t1;
    }
    __syncthreads();
  }

  // ---------- Phase 1b: wave 7 publishes z'[row][255] = sum(x_row) (ones column)
  if (w == 7 && l15 == 15) {
#pragma unroll
    for (int mt = 0; mt < 4; ++mt)
#pragma unroll
      for (int r4 = 0; r4 < 4; ++r4)
        z255s[(mt << 4) + (lq << 2) + r4] = acc[mt][1][r4];
  }
  __syncthreads();

  // ---------- Phase 2: sigmoid((z' + 0.5*z255 - c)*alpha) -> s_sig (col ^ (row&15))
#pragma unroll
  for (int ntl = 0; ntl < 2; ++ntl) {
    const int col = (w << 5) + (ntl << 4) + l15;
    const float cv = ntl ? cv1 : cv0;
#pragma unroll
    for (int mt = 0; mt < 4; ++mt) {
#pragma unroll
      for (int r4 = 0; r4 < 4; ++r4) {
        const int r = (mt << 4) + (lq << 2) + r4;
        const float z = (acc[mt][ntl][r4] + 0.5f * z255s[r] - cv) * alphav;
        const float s = 1.f / (1.f + __expf(-z));
        s_sig[(r << 8) + (col ^ (r & 15))] = s;
      }
    }
  }
  __syncthreads();

  // ---------- Phase 3+4: in-register leaf probs (single bf16) -> p@A MFMA.
  const int mt3 = w & 3;
  const int kh = w >> 2;
  const int arow = (mt3 << 4) + l15;
  const float* srow_p = s_sig + (arow << 8);
  const int sw = arow & 15;

  // hoisted tree levels 0..2 (constant across the ks loop for fixed kh)
  const float s0v = srow_p[0 ^ sw];
  const float s1v = srow_p[(1 + kh) ^ sw];
  const float f0 = kh ? (1.f - s0v) : s0v;
  const float pre01_0 = f0 * s1v;
  const float pre01_1 = f0 - f0 * s1v;
  const int n2b_ = 3 + (kh << 1);
  const float s2a = srow_p[n2b_ ^ sw];
  const float s2b = srow_p[(n2b_ + 1) ^ sw];

  f32x4 acc2[4];
#pragma unroll
  for (int i = 0; i < 4; ++i) acc2[i] = {0.f, 0.f, 0.f, 0.f};

#pragma unroll
  for (int ks = 0; ks < 4; ++ks) {
    // hoist AT fragment loads — tree walk covers L2 latency
    short8v bhv[4];
#pragma unroll
    for (int nt = 0; nt < 4; ++nt) {
      const int fb = ((((kh << 2) + ks) << 2) + nt) * 512 + (lane << 3);
      bhv[nt] = *reinterpret_cast<const short8v*>(ATf + fb);
    }

    const int lb = (kh << 7) + (ks << 5) + (lq << 3);
    // levels 0-2 from hoisted values
    const float pre01 = (ks & 2) ? pre01_1 : pre01_0;
    const float s2 = (ks & 2) ? s2b : s2a;
    float P = pre01 * ((ks & 1) ? (1.f - s2) : s2);
    // level 3: node 7+4kh+ks, dir = lq>>1
    const float s3 = srow_p[(7 + (kh << 2) + ks) ^ sw];
    P *= (lq >> 1) ? (1.f - s3) : s3;
    // level 4: node 15+8kh+2ks+(lq>>1), dir = lq&1
    const float s4 = srow_p[(15 + (kh << 3) + (ks << 1) + (lq >> 1)) ^ sw];
    P *= (lq & 1) ? (1.f - s4) : s4;
    // levels 5-7 per 8-leaf chunk
    const float s5 = srow_p[(31 + (lb >> 3)) ^ sw];
    const int n6 = 63 + (lb >> 2);
    const float s6a = srow_p[n6 ^ sw];
    const float s6b = srow_p[(n6 + 1) ^ sw];
    const int n7 = 127 + (lb >> 1);
    const float s7_0 = srow_p[n7 ^ sw];
    const float s7_1 = srow_p[(n7 + 1) ^ sw];
    const float s7_2 = srow_p[(n7 + 2) ^ sw];
    const float s7_3 = srow_p[(n7 + 3) ^ sw];
    const float q0 = P * s5, q1 = P - P * s5;
    const float r00 = q0 * s6a, r01 = q0 - q0 * s6a;
    const float r10 = q1 * s6b, r11 = q1 - q1 * s6b;
    float p[8];
    p[0] = r00 * s7_0; p[1] = r00 - p[0];
    p[2] = r01 * s7_1; p[3] = r01 - p[2];
    p[4] = r10 * s7_2; p[5] = r10 - p[4];
    p[6] = r11 * s7_3; p[7] = r11 - p[6];
    // packed bf16 p fragment via cvt_pk
    u32x4 pk;
    pk[0] = cvt_pk_bf16(p[0], p[1]);
    pk[1] = cvt_pk_bf16(p[2], p[3]);
    pk[2] = cvt_pk_bf16(p[4], p[5]);
    pk[3] = cvt_pk_bf16(p[6], p[7]);
    const short8v pah = __builtin_bit_cast(short8v, pk);
#pragma unroll
    for (int nt = 0; nt < 4; ++nt)
      acc2[nt] = __builtin_amdgcn_mfma_f32_16x16x32_bf16(pah, bhv[nt], acc2[nt], 0, 0, 0);
  }
  __syncthreads();  // all waves done reading s_sig

  // ---------- Phase 4b: ALL waves write partials to part[kh][64][68]
#pragma unroll
  for (int nt = 0; nt < 4; ++nt)
#pragma unroll
    for (int r4 = 0; r4 < 4; ++r4)
      part[(kh * 64 + (mt3 << 4) + (lq << 2) + r4) * 68 + (nt << 4) + l15] = acc2[nt][r4];
  __syncthreads();

  // ---------- Phase 5: vectorized reduce + softmax + dwordx4 stores.
  {
    const int r = tid >> 3;
    const int g = tid & 7;
    const float* p0 = part + (r * 68) + (g << 3);
    const float* p1 = part + ((64 + r) * 68) + (g << 3);
    f32x4 a0 = *reinterpret_cast<const f32x4*>(p0);
    f32x4 a1 = *reinterpret_cast<const f32x4*>(p0 + 4);
    f32x4 b0 = *reinterpret_cast<const f32x4*>(p1);
    f32x4 b1 = *reinterpret_cast<const f32x4*>(p1 + 4);
    float v[8];
#pragma unroll
    for (int i = 0; i < 4; ++i) { v[i] = a0[i] + b0[i]; v[4 + i] = a1[i] + b1[i]; }
    float m = v[0];
#pragma unroll
    for (int i = 1; i < 8; ++i) m = fmaxf(m, v[i]);
#pragma unroll
    for (int d = 1; d < 8; d <<= 1) m = fmaxf(m, __shfl_xor(m, d, 64));
    float e[8];
    float ssum = 0.f;
#pragma unroll
    for (int i = 0; i < 8; ++i) { e[i] = __expf(v[i] - m); ssum += e[i]; }
#pragma unroll
    for (int d = 1; d < 8; d <<= 1) ssum += __shfl_xor(ssum, d, 64);
    const float inv = 1.f / ssum;
    f32x4 o0, o1;
#pragma unroll
    for (int i = 0; i < 4; ++i) { o0[i] = e[i] * inv; o1[i] = e[4 + i] * inv; }
    float* op = out + (size_t)(row0 + r) * ODIM + (g << 3);
    *reinterpret_cast<f32x4*>(op) = o0;
    *reinterpret_cast<f32x4*>(op + 4) = o1;
  }
}

extern "C" void kernel_launch(void* const* d_in, const int* in_sizes, int n_in,
                              void* d_out, int out_size, void* d_ws, size_t ws_size,
                              hipStream_t stream) {
  const float* x      = (const float*)d_in[0];
  const float* layers = (const float*)d_in[1];
  const float* comp   = (const float*)d_in[2];
  const float* alpha  = (const float*)d_in[3];
  const float* aprobs = (const float*)d_in[4];
  float* out = (float*)d_out;

  const size_t wsz  = (size_t)131072;
  const size_t atsz = (size_t)16384;
  if (ws_size < (wsz + atsz) * sizeof(u16)) return;

  u16* Wf  = (u16*)d_ws;
  u16* ATf = Wf + wsz;

  const int prep_items = 131072 + 16384;
  prep_kernel<<<dim3((prep_items + 255) / 256), dim3(256), 0, stream>>>(
      layers, aprobs, Wf, ATf);

  prolo_main<<<dim3(32768 / BM), dim3(512), 0, stream>>>(
      x, comp, alpha, Wf, ATf, out);
}